// Round 15
// baseline (20.019 us; speedup 1.0000x reference)
//
#include <hip/hip_runtime.h>
#include <hip/hip_bf16.h>

// Problem dims (fixed): n=128, d=256, ic=16, oc=16, r=10
// x:   [n, d, ic, r]  f32; w: [d, ic, oc, r] f32; out: [n, d, oc, r] f32
// out[n,d,oc,r] = log( sum_ic exp(x)*exp(w) ) - log( sum_ic exp(w) )
//
// v15: prep kernel bakes exp(w) into MFMA-B-fragment order (wfrag) + lcs in
// d_ws (1.47 MB, L2-resident; same-XCD reuse by construction). Main kernel:
// block = (2 adjacent d, 16 n) -> x reads in contiguous 1280B spans; B-frags
// and lcs load straight to registers (kg<2; kg>=2 lanes use zero frags =
// K-pad, exact); es LDS only (21 KB), ONE barrier. MFMA slot-symmetric
// (v13/v14-verified), C layout col=lane&15, row=(lane>>4)*4+j (m89).

typedef __attribute__((ext_vector_type(8))) short bf16x8;
typedef __attribute__((ext_vector_type(4))) float f32x4;

#define LCS_OFF 1310720   // bytes: wfrag = 256 d * 10 r * 512 B = 1,310,720

__device__ __forceinline__ unsigned short f2bf(float v) {
    unsigned u = __float_as_uint(v);
    u += 0x7FFF + ((u >> 16) & 1);
    return (unsigned short)(u >> 16);
}

// ---------------- prep: wfrag[(d*10+r)*128 + lane*4 + wsel] + lcs -----------
__global__ __launch_bounds__(256) void prep_kernel(const float* __restrict__ w,
                                                   void* __restrict__ ws) {
    __shared__ float lexp[2560];         // [(ic*16+oc)*10 + r]
    const int d   = blockIdx.x;
    const int tid = threadIdx.x;         // = ic*16 + oc
    const int ic  = tid >> 4, oc = tid & 15;

    const float* wp = w + d * 2560 + ic * 160 + oc * 10;
#pragma unroll
    for (int k = 0; k < 5; ++k) {
        float2 v = *reinterpret_cast<const float2*>(wp + 2 * k);
        lexp[tid * 10 + 2 * k]     = __expf(v.x);
        lexp[tid * 10 + 2 * k + 1] = __expf(v.y);
    }
    __syncthreads();

    // lcs[d*160 + oc*10 + r]
    if (tid < 160) {
        const int o2 = tid / 10, rr = tid - (tid / 10) * 10;
        float s = 0.f;
#pragma unroll
        for (int i2 = 0; i2 < 16; ++i2) s += lexp[(i2 * 16 + o2) * 10 + rr];
        float* lcs = reinterpret_cast<float*>(reinterpret_cast<char*>(ws) + LCS_OFF);
        lcs[d * 160 + tid] = __logf(s);
    }

    // wfrag: per (d,r): 128 words; word idx = lane*4 + wsel, lane=(kg<2,oc),
    // shorts = slots kg*8 + 2wsel, +1 (slot == ic)
    unsigned* wf = reinterpret_cast<unsigned*>(ws);
    const int idx    = tid & 127;
    const int lane32 = idx >> 2;
    const int wsel   = idx & 3;
    const int kg     = lane32 >> 4;
    const int oc2    = lane32 & 15;
    const int s0     = kg * 8 + wsel * 2;
#pragma unroll
    for (int rr2 = 0; rr2 < 5; ++rr2) {
        const int r = rr2 * 2 + (tid >> 7);
        const unsigned lo = f2bf(lexp[(s0 * 16 + oc2) * 10 + r]);
        const unsigned hi = f2bf(lexp[((s0 + 1) * 16 + oc2) * 10 + r]);
        wf[(d * 10 + r) * 128 + idx] = lo | (hi << 16);
    }
}

// ---------------- main: 1024 blocks x 128 thr, one barrier ------------------
__global__ __launch_bounds__(128, 3) void main_kernel(const float* __restrict__ x,
                                                      const void* __restrict__ ws,
                                                      float* __restrict__ out) {
    // es[(d_l*16 + n_l)][r*32 + slot] bf16, row stride 328 shorts (v14-proven)
    __shared__ __align__(16) unsigned short es[32 * 328];    // 21 KB

    const int tid  = threadIdx.x;
    const int dg   = blockIdx.x & 127;   // d-pair index
    const int nc   = blockIdx.x >> 7;    // n-chunk 0..7
    const int wid  = tid >> 6;           // wave = d_local 0..1
    const int lane = tid & 63;
    const int lm   = lane & 15;
    const int kg   = lane >> 4;
    const int d_g  = dg * 2 + wid;
    const int n_b  = nc * 16;

    // ---- issue B-fragment + lcs loads to registers (L2-hot) -----------------
    bf16x8 bfr[10];
    const unsigned* wf = reinterpret_cast<const unsigned*>(ws);
#pragma unroll
    for (int r = 0; r < 10; ++r) {
        if (lane < 32) {
            bfr[r] = *reinterpret_cast<const bf16x8*>(&wf[(d_g * 10 + r) * 128 + lane * 4]);
        } else {
            bfr[r] = bf16x8{0, 0, 0, 0, 0, 0, 0, 0};   // K-pad slots 16..31
        }
    }
    float lc[10];
    {
        const float* lcs = reinterpret_cast<const float*>(
            reinterpret_cast<const char*>(ws) + LCS_OFF) + d_g * 160 + lm * 10;
#pragma unroll
        for (int k = 0; k < 5; ++k) {
            float2 v = *reinterpret_cast<const float2*>(lcs + 2 * k);
            lc[2 * k] = v.x; lc[2 * k + 1] = v.y;
        }
    }

    // ---- stage exp(x): thread = (n_l, d_l, seg); 1280B contiguous per (n,2d)
    {
        const int n_l = tid >> 3;        // 0..15
        const int sub = tid & 7;
        const int d_l = sub >> 2;        // 0..1
        const int seg = sub & 3;         // 0..3
        const float* xg = x + ((n_b + n_l) * 256 + dg * 2 + d_l) * 160 + seg * 40;
        float4 xv[10];
#pragma unroll
        for (int k = 0; k < 10; ++k) xv[k] = *reinterpret_cast<const float4*>(xg + 4 * k);
        const float* xf = reinterpret_cast<const float*>(xv);
        const int row = d_l * 16 + n_l;
#pragma unroll
        for (int r = 0; r < 10; ++r) {
            const unsigned lo = (unsigned)f2bf(__expf(xf[r]))      | ((unsigned)f2bf(__expf(xf[10 + r])) << 16);
            const unsigned hi = (unsigned)f2bf(__expf(xf[20 + r])) | ((unsigned)f2bf(__expf(xf[30 + r])) << 16);
            unsigned* dst = reinterpret_cast<unsigned*>(&es[row * 328 + r * 32 + seg * 4]);
            *reinterpret_cast<uint2*>(dst) = make_uint2(lo, hi);
            unsigned* pad = reinterpret_cast<unsigned*>(&es[row * 328 + r * 32 + 16 + seg * 4]);
            *reinterpret_cast<uint2*>(pad) = make_uint2(0u, 0u);
        }
    }
    __syncthreads();

    // ---- MFMA: A from LDS, B from regs --------------------------------------
    const int abase = (wid * 16 + lm) * 328 + kg * 8;
    f32x4 acc[10];
    const f32x4 zero = {0.f, 0.f, 0.f, 0.f};
#pragma unroll
    for (int r = 0; r < 10; ++r) {
        bf16x8 a = *reinterpret_cast<const bf16x8*>(&es[abase + r * 32]);
        acc[r] = __builtin_amdgcn_mfma_f32_16x16x32_bf16(a, bfr[r], zero, 0, 0, 0);
    }

    // ---- epilogue: C col=lm(oc), row=kg*4+j(n-local); direct stores ---------
#pragma unroll
    for (int j = 0; j < 4; ++j) {
        const int n = n_b + kg * 4 + j;
        float* og = out + (n * 256 + d_g) * 160 + lm * 10;
#pragma unroll
        for (int h = 0; h < 5; ++h) {
            float2 o;
            o.x = __logf(acc[2 * h][j])     - lc[2 * h];
            o.y = __logf(acc[2 * h + 1][j]) - lc[2 * h + 1];
            *reinterpret_cast<float2*>(og + 2 * h) = o;
        }
    }
}

extern "C" void kernel_launch(void* const* d_in, const int* in_sizes, int n_in,
                              void* d_out, int out_size, void* d_ws, size_t ws_size,
                              hipStream_t stream) {
    const float* x = (const float*)d_in[0];
    const float* w = (const float*)d_in[1];
    float* out = (float*)d_out;

    prep_kernel<<<256, 256, 0, stream>>>(w, d_ws);
    // 1024 blocks: dg = bid&127 (d-pair), nc = bid>>7; nc-partners share XCD
    main_kernel<<<1024, 128, 0, stream>>>(x, d_ws, out);
}